// Round 1
// baseline (330.302 us; speedup 1.0000x reference)
//
#include <hip/hip_runtime.h>

// q = rownorm( 1 / (1 + ||x - c||^2) ), ALPHA=1
// x: (262144, 256) f32 ; clusters: (256, 256) f32 ; out: (262144, 256) f32
//
// Strategy: cross = x @ clusters^T via bf16 MFMA 16x16x32 (fp32 accum),
// fused student-t + row-normalize epilogue. clusters pre-converted to bf16
// in d_ws (L2-resident, no LDS staging needed at 128 KB).

#define NROWS 262144
#define DDIM  256
#define KCL   256

using f32x4  = __attribute__((ext_vector_type(4))) float;
using s16x8  = __attribute__((ext_vector_type(8))) short;

__device__ inline unsigned short f2bf(float f) {
    // round-to-nearest-even f32 -> bf16
    unsigned int u = __float_as_uint(f);
    u += 0x7fffu + ((u >> 16) & 1u);
    return (unsigned short)(u >> 16);
}

// One wave per cluster row: convert to bf16, compute ||c||^2.
__global__ void prep_kernel(const float* __restrict__ clusters,
                            unsigned short* __restrict__ cb,
                            float* __restrict__ csq) {
    int k    = blockIdx.x;
    int lane = threadIdx.x;  // 64 threads
    const float* row = clusters + (size_t)k * DDIM;
    float4 a = *reinterpret_cast<const float4*>(row + lane * 4);
    ushort4 b;
    b.x = f2bf(a.x); b.y = f2bf(a.y); b.z = f2bf(a.z); b.w = f2bf(a.w);
    *reinterpret_cast<ushort4*>(cb + (size_t)k * DDIM + lane * 4) = b;
    float ss = a.x*a.x + a.y*a.y + a.z*a.z + a.w*a.w;
    #pragma unroll
    for (int m = 1; m < 64; m <<= 1) ss += __shfl_xor(ss, m);
    if (lane == 0) csq[k] = ss;
}

// 4 waves/block; wave owns 16 rows x 256 cols.
// A-frag: lane holds x[row0 + (l&15)][kbase + (l>>4)*8 + j], j=0..7
// B-frag: lane holds c [16f  + (l&15)][kbase + (l>>4)*8 + j]  (= B^T, k contiguous)
// C/D   : col = l&15, row = (l>>4)*4 + reg   [verified layout, m89]
__global__ __launch_bounds__(256) void fused_kernel(
    const float* __restrict__ x,
    const unsigned short* __restrict__ cb,
    const float* __restrict__ csq,
    float* __restrict__ out) {

    const int tid  = threadIdx.x;
    const int lane = tid & 63;
    const int wave = tid >> 6;
    const int c15  = lane & 15;
    const int kch  = lane >> 4;           // 0..3
    const int row0 = blockIdx.x * 64 + wave * 16;

    const float*          xrow  = x  + (size_t)(row0 + c15) * DDIM;
    const unsigned short* bbase = cb + (size_t)c15 * DDIM + kch * 8;

    f32x4 acc[16];
    #pragma unroll
    for (int f = 0; f < 16; ++f) acc[f] = (f32x4){0.f, 0.f, 0.f, 0.f};
    float xsq = 0.f;

    for (int step = 0; step < 8; ++step) {
        const int kbase = step * 32 + kch * 8;
        float4 xa = *reinterpret_cast<const float4*>(xrow + kbase);
        float4 xb = *reinterpret_cast<const float4*>(xrow + kbase + 4);
        xsq += xa.x*xa.x + xa.y*xa.y + xa.z*xa.z + xa.w*xa.w
             + xb.x*xb.x + xb.y*xb.y + xb.z*xb.z + xb.w*xb.w;
        s16x8 afrag;
        afrag[0] = (short)f2bf(xa.x); afrag[1] = (short)f2bf(xa.y);
        afrag[2] = (short)f2bf(xa.z); afrag[3] = (short)f2bf(xa.w);
        afrag[4] = (short)f2bf(xb.x); afrag[5] = (short)f2bf(xb.y);
        afrag[6] = (short)f2bf(xb.z); afrag[7] = (short)f2bf(xb.w);

        const unsigned short* bptr = bbase + step * 32;
        #pragma unroll
        for (int f = 0; f < 16; ++f) {
            s16x8 bfrag = *reinterpret_cast<const s16x8*>(bptr + (size_t)f * 16 * DDIM);
            acc[f] = __builtin_amdgcn_mfma_f32_16x16x32_bf16(afrag, bfrag, acc[f], 0, 0, 0);
        }
    }

    // full ||x||^2 per A-row: combine the 4 k-chunk partials (lanes r, r+16, r+32, r+48)
    xsq += __shfl_xor(xsq, 16);
    xsq += __shfl_xor(xsq, 32);
    // now lane l holds xsq of row (l&15)

    float cs[16];
    #pragma unroll
    for (int f = 0; f < 16; ++f) cs[f] = csq[f * 16 + c15];

    float inv_r[4];
    #pragma unroll
    for (int r = 0; r < 4; ++r) {
        // output row for this (lane, reg): kch*4 + r ; fetch its xsq from lane (kch*4+r)
        float xr = __shfl(xsq, kch * 4 + r);
        float s = 0.f;
        #pragma unroll
        for (int f = 0; f < 16; ++f) {
            float d2 = xr - 2.0f * acc[f][r] + cs[f];
            float qv = 1.0f / (1.0f + d2);   // ALPHA=1 -> exponent (ALPHA+1)/2 == 1
            acc[f][r] = qv;
            s += qv;
        }
        // row-sum across the 16 cols held by this 16-lane group, x16 fragments
        s += __shfl_xor(s, 1);
        s += __shfl_xor(s, 2);
        s += __shfl_xor(s, 4);
        s += __shfl_xor(s, 8);
        inv_r[r] = 1.0f / s;
    }

    #pragma unroll
    for (int r = 0; r < 4; ++r) {
        const size_t orow = (size_t)(row0 + kch * 4 + r) * KCL;
        #pragma unroll
        for (int f = 0; f < 16; ++f) {
            out[orow + f * 16 + c15] = acc[f][r] * inv_r[r];
        }
    }
}

extern "C" void kernel_launch(void* const* d_in, const int* in_sizes, int n_in,
                              void* d_out, int out_size, void* d_ws, size_t ws_size,
                              hipStream_t stream) {
    const float* x        = (const float*)d_in[0];
    const float* clusters = (const float*)d_in[1];
    float* out = (float*)d_out;

    // ws layout: [0, 128KB) clusters as bf16 ; [128KB, +1KB) c_sq f32
    unsigned short* cb  = (unsigned short*)d_ws;
    float*          csq = (float*)((char*)d_ws + (size_t)KCL * DDIM * sizeof(unsigned short));

    prep_kernel<<<KCL, 64, 0, stream>>>(clusters, cb, csq);
    fused_kernel<<<NROWS / 64, 256, 0, stream>>>(x, cb, csq, out);
}

// Round 2
// 245.542 us; speedup vs baseline: 1.3452x; 1.3452x over previous
//
#include <hip/hip_runtime.h>

// q = rownorm( 1 / (1 + ||x - c||^2) ), ALPHA=1
// x: (262144, 256) f32 ; clusters: (256, 256) f32 ; out: (262144, 256) f32
//
// R2: latency fixes. (1) x-rows preloaded to registers up-front (one HBM
// round-trip per wave, not 8). (2) B staged in LDS in 32KB chunks via
// global_load_lds w=16, XOR-swizzled on the GLOBAL source (LDS dest linear,
// per m104/m173) so the B-frag ds_read_b128 is conflict-free.

#define NROWS 262144
#define DDIM  256
#define KCL   256
#define CHUNK 64            // clusters per LDS chunk (32 KB bf16)

using f32x4  = __attribute__((ext_vector_type(4))) float;
using s16x8  = __attribute__((ext_vector_type(8))) short;

__device__ inline unsigned short f2bf(float f) {
    // round-to-nearest-even f32 -> bf16
    unsigned int u = __float_as_uint(f);
    u += 0x7fffu + ((u >> 16) & 1u);
    return (unsigned short)(u >> 16);
}

// One wave per cluster row: convert to bf16, compute ||c||^2.
__global__ void prep_kernel(const float* __restrict__ clusters,
                            unsigned short* __restrict__ cb,
                            float* __restrict__ csq) {
    int k    = blockIdx.x;
    int lane = threadIdx.x;  // 64 threads
    const float* row = clusters + (size_t)k * DDIM;
    float4 a = *reinterpret_cast<const float4*>(row + lane * 4);
    ushort4 b;
    b.x = f2bf(a.x); b.y = f2bf(a.y); b.z = f2bf(a.z); b.w = f2bf(a.w);
    *reinterpret_cast<ushort4*>(cb + (size_t)k * DDIM + lane * 4) = b;
    float ss = a.x*a.x + a.y*a.y + a.z*a.z + a.w*a.w;
    #pragma unroll
    for (int m = 1; m < 64; m <<= 1) ss += __shfl_xor(ss, m);
    if (lane == 0) csq[k] = ss;
}

// 4 waves/block; wave owns 16 rows x 256 cols.
// A-frag: lane holds x[row0 + (l&15)][kbase + (l>>4)*8 + j], j=0..7
// B-frag: lane holds c [cl]         [kbase + (l>>4)*8 + j], cl = chunk*64+f*16+(l&15)
// C/D   : col = l&15, row = (l>>4)*4 + reg   [verified layout, m89]
__global__ __launch_bounds__(256, 4) void fused_kernel(
    const float* __restrict__ x,
    const unsigned short* __restrict__ cb,
    const float* __restrict__ csq,
    float* __restrict__ out) {

    __shared__ char lds_b[CHUNK * DDIM * 2];   // 32 KB, one B chunk (swizzled)

    const int tid  = threadIdx.x;
    const int lane = tid & 63;
    const int wave = tid >> 6;
    const int c15  = lane & 15;
    const int kch  = lane >> 4;           // 0..3
    const int row0 = blockIdx.x * 64 + wave * 16;

    const float* xrow = x + (size_t)(row0 + c15) * DDIM;

    // ---- preload this wave's 16 x-rows as bf16 A-frags, accumulate ||x||^2 ----
    s16x8 afrag[8];
    float xsq = 0.f;
    #pragma unroll
    for (int step = 0; step < 8; ++step) {
        const int kbase = step * 32 + kch * 8;
        float4 xa = *reinterpret_cast<const float4*>(xrow + kbase);
        float4 xb = *reinterpret_cast<const float4*>(xrow + kbase + 4);
        xsq += xa.x*xa.x + xa.y*xa.y + xa.z*xa.z + xa.w*xa.w
             + xb.x*xb.x + xb.y*xb.y + xb.z*xb.z + xb.w*xb.w;
        afrag[step][0] = (short)f2bf(xa.x); afrag[step][1] = (short)f2bf(xa.y);
        afrag[step][2] = (short)f2bf(xa.z); afrag[step][3] = (short)f2bf(xa.w);
        afrag[step][4] = (short)f2bf(xb.x); afrag[step][5] = (short)f2bf(xb.y);
        afrag[step][6] = (short)f2bf(xb.z); afrag[step][7] = (short)f2bf(xb.w);
    }

    f32x4 acc[16];
    #pragma unroll
    for (int f = 0; f < 16; ++f) acc[f] = (f32x4){0.f, 0.f, 0.f, 0.f};

    // ---- loop over 4 B chunks: stage 32 KB in LDS, 32 MFMAs per chunk ----
    for (int c = 0; c < 4; ++c) {
        const char* gb = (const char*)cb + (size_t)c * CHUNK * DDIM * 2;
        #pragma unroll
        for (int it = 0; it < 8; ++it) {
            // linear LDS byte slot for this lane; swizzle the GLOBAL source
            int slot = (it * 4 + wave) * 1024 + lane * 16;
            int src  = slot ^ (((slot >> 9) & 7) << 4);
            __builtin_amdgcn_global_load_lds(
                (const __attribute__((address_space(1))) unsigned int*)(gb + src),
                (__attribute__((address_space(3))) unsigned int*)(lds_b + slot),
                16, 0, 0);
        }
        __syncthreads();   // drains vmcnt before barrier

        #pragma unroll
        for (int step = 0; step < 8; ++step) {
            #pragma unroll
            for (int f = 0; f < 4; ++f) {
                // B byte addr within chunk, then read-side swizzle (involution)
                int ba = (f * 16 + c15) * 512 + step * 64 + kch * 16;
                ba ^= ((c15 & 7) << 4);
                s16x8 bfrag = *reinterpret_cast<const s16x8*>(lds_b + ba);
                acc[c * 4 + f] =
                    __builtin_amdgcn_mfma_f32_16x16x32_bf16(afrag[step], bfrag,
                                                            acc[c * 4 + f], 0, 0, 0);
            }
        }
        __syncthreads();   // before next chunk overwrites LDS
    }

    // ---- epilogue: student-t + row-normalize, fused ----
    // combine the 4 k-chunk xsq partials (lanes r, r+16, r+32, r+48)
    xsq += __shfl_xor(xsq, 16);
    xsq += __shfl_xor(xsq, 32);
    // now lane l holds xsq of row (l&15)

    float cs[16];
    #pragma unroll
    for (int f = 0; f < 16; ++f) cs[f] = csq[f * 16 + c15];

    float inv_r[4];
    #pragma unroll
    for (int r = 0; r < 4; ++r) {
        // output row for this (lane, reg): kch*4 + r ; fetch its xsq
        float xr = __shfl(xsq, kch * 4 + r);
        float s = 0.f;
        #pragma unroll
        for (int f = 0; f < 16; ++f) {
            float d2 = xr - 2.0f * acc[f][r] + cs[f];
            float qv = 1.0f / (1.0f + d2);   // ALPHA=1 -> exponent == 1
            acc[f][r] = qv;
            s += qv;
        }
        s += __shfl_xor(s, 1);
        s += __shfl_xor(s, 2);
        s += __shfl_xor(s, 4);
        s += __shfl_xor(s, 8);
        inv_r[r] = 1.0f / s;
    }

    #pragma unroll
    for (int r = 0; r < 4; ++r) {
        const size_t orow = (size_t)(row0 + kch * 4 + r) * KCL;
        #pragma unroll
        for (int f = 0; f < 16; ++f) {
            out[orow + f * 16 + c15] = acc[f][r] * inv_r[r];
        }
    }
}

extern "C" void kernel_launch(void* const* d_in, const int* in_sizes, int n_in,
                              void* d_out, int out_size, void* d_ws, size_t ws_size,
                              hipStream_t stream) {
    const float* x        = (const float*)d_in[0];
    const float* clusters = (const float*)d_in[1];
    float* out = (float*)d_out;

    // ws layout: [0, 128KB) clusters as bf16 ; [128KB, +1KB) c_sq f32
    unsigned short* cb  = (unsigned short*)d_ws;
    float*          csq = (float*)((char*)d_ws + (size_t)KCL * DDIM * sizeof(unsigned short));

    prep_kernel<<<KCL, 64, 0, stream>>>(clusters, cb, csq);
    fused_kernel<<<NROWS / 64, 256, 0, stream>>>(x, cb, csq, out);
}

// Round 3
// 150.186 us; speedup vs baseline: 2.1993x; 1.6349x over previous
//
#include <hip/hip_runtime.h>

// q = rownorm( 1 / (1 + ||x - c||^2) ), ALPHA=1
// x: (262144, 256) f32 ; clusters: (256, 256) f32 ; out: (262144, 256) f32
//
// R3: streaming structure. Full B (128 KB bf16, swizzled) staged in LDS ONCE
// per block -> no steady-state barriers. 1 block/CU (4 waves, 1/SIMD) with a
// 512-reg/wave budget (launch_bounds(256,1)) -> no spill (R2's launch_bounds
// (256,4) spilled ~370 MB to scratch). Each block processes 8 row-tiles with
// double-buffered register prefetch so HBM requests stream continuously.

#define NROWS 262144
#define DDIM  256
#define KCL   256
#define TPB   8          // row-tiles (64 rows) per block
#define GRID  (NROWS / 64 / TPB)   // 512 blocks

using f32x4  = __attribute__((ext_vector_type(4))) float;
using s16x8  = __attribute__((ext_vector_type(8))) short;

__device__ inline unsigned short f2bf(float f) {
    // round-to-nearest-even f32 -> bf16
    unsigned int u = __float_as_uint(f);
    u += 0x7fffu + ((u >> 16) & 1u);
    return (unsigned short)(u >> 16);
}

// One wave per cluster row: convert to bf16, compute ||c||^2.
__global__ void prep_kernel(const float* __restrict__ clusters,
                            unsigned short* __restrict__ cb,
                            float* __restrict__ csq) {
    int k    = blockIdx.x;
    int lane = threadIdx.x;  // 64 threads
    const float* row = clusters + (size_t)k * DDIM;
    float4 a = *reinterpret_cast<const float4*>(row + lane * 4);
    ushort4 b;
    b.x = f2bf(a.x); b.y = f2bf(a.y); b.z = f2bf(a.z); b.w = f2bf(a.w);
    *reinterpret_cast<ushort4*>(cb + (size_t)k * DDIM + lane * 4) = b;
    float ss = a.x*a.x + a.y*a.y + a.z*a.z + a.w*a.w;
    #pragma unroll
    for (int m = 1; m < 64; m <<= 1) ss += __shfl_xor(ss, m);
    if (lane == 0) csq[k] = ss;
}

// 4 waves/block; wave owns 16 rows x 256 cols per tile.
// A-frag: lane holds x[row0 + (l&15)][step*32 + (l>>4)*8 + j], j=0..7
// B-frag: lane holds c[f*16 + (l&15)][step*32 + (l>>4)*8 + j]
// C/D   : col = l&15, row = (l>>4)*4 + reg   [verified layout, m89]
__global__ __launch_bounds__(256, 1) void fused_kernel(
    const float* __restrict__ x,
    const unsigned short* __restrict__ cb,
    const float* __restrict__ csq,
    float* __restrict__ out) {

    __shared__ char lds_b[KCL * DDIM * 2];   // 128 KB: full B, swizzled

    const int tid  = threadIdx.x;
    const int lane = tid & 63;
    const int wave = tid >> 6;
    const int c15  = lane & 15;
    const int kch  = lane >> 4;           // 0..3

    const int tile0 = blockIdx.x * TPB;

    // per-lane base: row (tileRow + wave*16 + c15), col kch*8
    auto xbase = [&](int t) -> const float* {
        return x + (size_t)((tile0 + t) * 64 + wave * 16 + c15) * DDIM + kch * 8;
    };

    f32x4 stA[16], stB[16];

    // ---- issue first two tiles' x loads (in flight during B staging) ----
    #pragma unroll
    for (int i = 0; i < 16; ++i)
        stA[i] = *reinterpret_cast<const f32x4*>(xbase(0) + (i >> 1) * 32 + (i & 1) * 4);
    #pragma unroll
    for (int i = 0; i < 16; ++i)
        stB[i] = *reinterpret_cast<const f32x4*>(xbase(1) + (i >> 1) * 32 + (i & 1) * 4);

    // ---- stage full B into LDS (linear dest, swizzled global source) ----
    #pragma unroll
    for (int it = 0; it < 32; ++it) {
        int slot = it * 4096 + tid * 16;
        int src  = slot ^ (((slot >> 9) & 7) << 4);
        __builtin_amdgcn_global_load_lds(
            (const __attribute__((address_space(1))) unsigned int*)((const char*)cb + src),
            (__attribute__((address_space(3))) unsigned int*)(lds_b + slot),
            16, 0, 0);
    }

    // csq fragment for the epilogue (block-invariant)
    float cs[16];
    #pragma unroll
    for (int f = 0; f < 16; ++f) cs[f] = csq[f * 16 + c15];

    __syncthreads();   // drains vmcnt; B ready, stA/stB landed too

    s16x8 afrag[8];

    // ---- macro-free inline phases via lambdas (all static indexing) ----
    auto convert = [&](const f32x4* st, float& xsq) {
        xsq = 0.f;
        #pragma unroll
        for (int s = 0; s < 8; ++s) {
            f32x4 xa = st[2 * s], xb = st[2 * s + 1];
            xsq += xa[0]*xa[0] + xa[1]*xa[1] + xa[2]*xa[2] + xa[3]*xa[3]
                 + xb[0]*xb[0] + xb[1]*xb[1] + xb[2]*xb[2] + xb[3]*xb[3];
            afrag[s][0] = (short)f2bf(xa[0]); afrag[s][1] = (short)f2bf(xa[1]);
            afrag[s][2] = (short)f2bf(xa[2]); afrag[s][3] = (short)f2bf(xa[3]);
            afrag[s][4] = (short)f2bf(xb[0]); afrag[s][5] = (short)f2bf(xb[1]);
            afrag[s][6] = (short)f2bf(xb[2]); afrag[s][7] = (short)f2bf(xb[3]);
        }
    };

    auto compute_store = [&](int t, float xsq) {
        f32x4 acc[16];
        #pragma unroll
        for (int f = 0; f < 16; ++f) acc[f] = (f32x4){0.f, 0.f, 0.f, 0.f};

        #pragma unroll
        for (int f = 0; f < 16; ++f) {
            #pragma unroll
            for (int s = 0; s < 8; ++s) {
                int ba = (f * 16 + c15) * 512 + s * 64 + kch * 16;
                ba ^= ((c15 & 7) << 4);
                s16x8 bfrag = *reinterpret_cast<const s16x8*>(lds_b + ba);
                acc[f] = __builtin_amdgcn_mfma_f32_16x16x32_bf16(afrag[s], bfrag,
                                                                 acc[f], 0, 0, 0);
            }
        }

        // combine the 4 kch partials of ||x||^2 (lane l -> row l&15)
        xsq += __shfl_xor(xsq, 16);
        xsq += __shfl_xor(xsq, 32);

        const int row0t = (tile0 + t) * 64 + wave * 16;
        #pragma unroll
        for (int r = 0; r < 4; ++r) {
            float xr = __shfl(xsq, kch * 4 + r);
            float s = 0.f;
            #pragma unroll
            for (int f = 0; f < 16; ++f) {
                float d2 = xr - 2.0f * acc[f][r] + cs[f];
                float qv = 1.0f / (1.0f + d2);   // ALPHA=1 -> exponent == 1
                acc[f][r] = qv;
                s += qv;
            }
            s += __shfl_xor(s, 1);
            s += __shfl_xor(s, 2);
            s += __shfl_xor(s, 4);
            s += __shfl_xor(s, 8);
            float inv = 1.0f / s;
            const size_t orow = (size_t)(row0t + kch * 4 + r) * KCL;
            #pragma unroll
            for (int f = 0; f < 16; ++f) {
                out[orow + f * 16 + c15] = acc[f][r] * inv;
            }
        }
    };

    #pragma unroll 1
    for (int t = 0; t < TPB; t += 2) {
        float xsqA, xsqB;
        convert(stA, xsqA);                 // waits stA loads (long in flight)
        if (t + 2 < TPB) {                  // refill stA for tile t+2
            #pragma unroll
            for (int i = 0; i < 16; ++i)
                stA[i] = *reinterpret_cast<const f32x4*>(xbase(t + 2) + (i >> 1) * 32 + (i & 1) * 4);
        }
        compute_store(t, xsqA);             // MFMA hides stA(t+2) latency

        convert(stB, xsqB);
        if (t + 3 < TPB) {                  // refill stB for tile t+3
            #pragma unroll
            for (int i = 0; i < 16; ++i)
                stB[i] = *reinterpret_cast<const f32x4*>(xbase(t + 3) + (i >> 1) * 32 + (i & 1) * 4);
        }
        compute_store(t + 1, xsqB);
    }
}

extern "C" void kernel_launch(void* const* d_in, const int* in_sizes, int n_in,
                              void* d_out, int out_size, void* d_ws, size_t ws_size,
                              hipStream_t stream) {
    const float* x        = (const float*)d_in[0];
    const float* clusters = (const float*)d_in[1];
    float* out = (float*)d_out;

    // ws layout: [0, 128KB) clusters as bf16 ; [128KB, +1KB) c_sq f32
    unsigned short* cb  = (unsigned short*)d_ws;
    float*          csq = (float*)((char*)d_ws + (size_t)KCL * DDIM * sizeof(unsigned short));

    prep_kernel<<<KCL, 64, 0, stream>>>(clusters, cb, csq);
    fused_kernel<<<GRID, 256, 0, stream>>>(x, cb, csq, out);
}